// Round 9
// baseline (481.130 us; speedup 1.0000x reference)
//
#include <hip/hip_runtime.h>

#define D_IN_C 16
#define D_OUT_C 32
#define NB_LOG 6                 // 64 nodes per bucket
#define NB (1 << NB_LOG)         // 64
#define NB_MASK (NB - 1)
#define MAXBUCK 1600             // supports up to 102400 nodes
#define EPB 12800                // edges per block in hist/bin

// ---------------------------------------------------------------------------
// K1: h = relu(x@w1+b1)@w2+b2 ; zero bucket counts (new path) or
// summed/cnt (fallback path).
// ---------------------------------------------------------------------------
__global__ __launch_bounds__(256) void mlp_kernel(
    const float* __restrict__ x,
    const float* __restrict__ w1, const float* __restrict__ b1,
    const float* __restrict__ w2, const float* __restrict__ b2,
    float* __restrict__ h, float* __restrict__ summed, int* __restrict__ cnt,
    int* __restrict__ gcount, int nbuck, int n_nodes) {
  __shared__ float sw1[256];
  __shared__ float sw2[256];
  __shared__ float sb1[16];
  __shared__ float sb2[16];
  int t = threadIdx.x;
  sw1[t] = w1[t];
  sw2[t] = w2[t];
  if (t < 16) { sb1[t] = b1[t]; sb2[t] = b2[t]; }
  __syncthreads();

  int n = blockIdx.x * blockDim.x + t;

  if (gcount && n < nbuck) gcount[n] = 0;
  if (n >= n_nodes) return;

  float xi[16];
  const float4* xr = (const float4*)(x + (size_t)n * 16);
  float4 v0 = xr[0], v1 = xr[1], v2 = xr[2], v3 = xr[3];
  xi[0]=v0.x; xi[1]=v0.y; xi[2]=v0.z; xi[3]=v0.w;
  xi[4]=v1.x; xi[5]=v1.y; xi[6]=v1.z; xi[7]=v1.w;
  xi[8]=v2.x; xi[9]=v2.y; xi[10]=v2.z; xi[11]=v2.w;
  xi[12]=v3.x; xi[13]=v3.y; xi[14]=v3.z; xi[15]=v3.w;

  float t1[16];
#pragma unroll
  for (int j = 0; j < 16; ++j) {
    float acc = sb1[j];
#pragma unroll
    for (int k = 0; k < 16; ++k) acc += xi[k] * sw1[k * 16 + j];
    t1[j] = fmaxf(acc, 0.0f);
  }
  float hh[16];
#pragma unroll
  for (int j = 0; j < 16; ++j) {
    float acc = sb2[j];
#pragma unroll
    for (int k = 0; k < 16; ++k) acc += t1[k] * sw2[k * 16 + j];
    hh[j] = acc;
  }

  float4* hw = (float4*)(h + (size_t)n * 16);
  hw[0] = make_float4(hh[0], hh[1], hh[2], hh[3]);
  hw[1] = make_float4(hh[4], hh[5], hh[6], hh[7]);
  hw[2] = make_float4(hh[8], hh[9], hh[10], hh[11]);
  hw[3] = make_float4(hh[12], hh[13], hh[14], hh[15]);

  if (cnt) cnt[n] = 0;
  if (summed) {
    float4* sz = (float4*)(summed + (size_t)n * 16);
    float4 z = make_float4(0.f, 0.f, 0.f, 0.f);
    sz[0] = z; sz[1] = z; sz[2] = z; sz[3] = z;
  }
}

// ---------------------------------------------------------------------------
// K2: per-bucket histogram, LDS-aggregated per block.
// ---------------------------------------------------------------------------
__global__ __launch_bounds__(1024) void hist_kernel(
    const int* __restrict__ dst, int* __restrict__ gcount,
    int nbuck, int n_edges) {
  __shared__ int lcnt[MAXBUCK];
  int t = threadIdx.x;
  for (int i = t; i < MAXBUCK; i += 1024) lcnt[i] = 0;
  __syncthreads();
  int e0 = blockIdx.x * EPB;
  int e1 = e0 + EPB; if (e1 > n_edges) e1 = n_edges;
  for (int e = e0 + t; e < e1; e += 1024)
    atomicAdd(&lcnt[dst[e] >> NB_LOG], 1);
  __syncthreads();
  for (int b = t; b < nbuck; b += 1024) {
    int c = lcnt[b];
    if (c) atomicAdd(&gcount[b], c);
  }
}

// ---------------------------------------------------------------------------
// K3: single-block exclusive scan over nbuck bucket counts.
// ---------------------------------------------------------------------------
__global__ __launch_bounds__(256) void scan_kernel(
    const int* __restrict__ gcount, int* __restrict__ base,
    int* __restrict__ cursor, int nbuck) {
  __shared__ int ps[256];
  int t = threadIdx.x;
  int per = (nbuck + 255) / 256;
  int beg = t * per;
  int end = beg + per; if (end > nbuck) end = nbuck;
  int sum = 0;
  for (int i = beg; i < end; ++i) sum += gcount[i];
  ps[t] = sum;
  __syncthreads();
#pragma unroll
  for (int off = 1; off < 256; off <<= 1) {
    int add = (t >= off) ? ps[t - off] : 0;
    __syncthreads();
    ps[t] += add;
    __syncthreads();
  }
  int run = ps[t] - sum;  // exclusive prefix
  for (int i = beg; i < end; ++i) {
    base[i] = run;
    cursor[i] = run;
    run += gcount[i];
  }
  if (t == 255) base[nbuck] = ps[255];
}

// ---------------------------------------------------------------------------
// K4: bin edges. Per block: LDS count -> span reservation -> LDS-rank
// scatter. pack = (src << 6) | (dst & 63)
// ---------------------------------------------------------------------------
__global__ __launch_bounds__(1024) void bin_kernel(
    const int* __restrict__ src, const int* __restrict__ dst,
    int* __restrict__ cursor, unsigned int* __restrict__ ebuf,
    int nbuck, int n_edges) {
  __shared__ int lcnt[MAXBUCK];
  __shared__ int lspan[MAXBUCK];
  int t = threadIdx.x;
  for (int i = t; i < MAXBUCK; i += 1024) lcnt[i] = 0;
  __syncthreads();
  int e0 = blockIdx.x * EPB;
  int e1 = e0 + EPB; if (e1 > n_edges) e1 = n_edges;
  // phase A: local count
  for (int e = e0 + t; e < e1; e += 1024)
    atomicAdd(&lcnt[dst[e] >> NB_LOG], 1);
  __syncthreads();
  // phase B: reserve spans, reset counters for rank pass
  for (int b = t; b < nbuck; b += 1024) {
    int c = lcnt[b];
    lspan[b] = c ? atomicAdd(&cursor[b], c) : 0;
    lcnt[b] = 0;
  }
  __syncthreads();
  // phase C: scatter
  for (int e = e0 + t; e < e1; e += 1024) {
    int d = dst[e];
    int b = d >> NB_LOG;
    int r = atomicAdd(&lcnt[b], 1);
    ebuf[lspan[b] + r] =
        ((unsigned int)src[e] << NB_LOG) | (unsigned int)(d & NB_MASK);
  }
}

// ---------------------------------------------------------------------------
// K5: per-bucket aggregate + fused SAGE epilogue.
// DMA GATHER via global_load_lds. Rounds 4-7 established a path-independent
// ~31-outstanding-line/CU cap on the normal vector-load path (four schemes,
// incl. asm-batched loads, all ~320us; Little's law from 205MB line demand
// at ~800ns latency). global_load_lds is the direct-to-LDS DMA path with
// per-lane GLOBAL source addresses (HW-verified semantics: dest = uniform
// LDS base + lane*4). Per wave: 8 ops x 4 rows/op = 32 lines in flight,
// tracked by vmcnt, not L1 return slots.
//   wave layout: lane = cl*16+k (cl=cluster 0..3, k=elem 0..15)
//   op u stages edges pb+4u+cl: lane addr = h + row(e)*64 + k*4
//   staging stg[wave][u][lane] then ds_read + LDS-atomic into ssum.
// ---------------------------------------------------------------------------
__global__ __launch_bounds__(256) void agg_out_kernel(
    const float* __restrict__ h, const unsigned int* __restrict__ ebuf,
    const int* __restrict__ base,
    const float* __restrict__ wl, const float* __restrict__ bl,
    const float* __restrict__ wr, float* __restrict__ out, int n_nodes) {
  __shared__ float ssum[NB * 16];     // 4 KB
  __shared__ int   scnt[NB];
  __shared__ float stg[4 * 8 * 64];   // 8 KB: [wave][op][lane]
  __shared__ float swl[512];
  __shared__ float swr[512];
  __shared__ float sbl[32];

  int t = threadIdx.x;
  int b = blockIdx.x;

  for (int i = t; i < 512; i += 256) { swl[i] = wl[i]; swr[i] = wr[i]; }
  if (t < 32) sbl[t] = bl[t];
#pragma unroll
  for (int i = t; i < NB * 16; i += 256) ssum[i] = 0.0f;
  if (t < NB) scnt[t] = 0;
  __syncthreads();

  int beg = base[b];
  int end = base[b + 1];

  int wid  = t >> 6;        // wave 0..3
  int lane = t & 63;
  int cl   = lane >> 4;     // cluster 0..3
  int k    = lane & 15;

  const char* hb = (const char*)h;
  float* stgw = &stg[wid * 512];

  // each wave: batches of 32 edges (8 DMA ops x 4 edges)
  for (int pb = beg + wid * 32; pb < end; pb += 128) {
    unsigned int e[8];
#pragma unroll
    for (int u = 0; u < 8; ++u) {
      int idx = pb + 4 * u + cl;
      int cidx = idx < end ? idx : end - 1;   // clamp: safe redundant entry
      e[u] = ebuf[cidx];
    }
#pragma unroll
    for (int u = 0; u < 8; ++u) {
      const void* gp = (const void*)(hb + ((e[u] & ~63u) + (unsigned)(k << 2)));
      __builtin_amdgcn_global_load_lds(
          (const __attribute__((address_space(1))) void*)gp,
          (__attribute__((address_space(3))) void*)&stgw[u * 64], 4, 0, 0);
    }
    asm volatile("s_waitcnt vmcnt(0)" ::: "memory");
#pragma unroll
    for (int u = 0; u < 8; ++u) {
      int idx = pb + 4 * u + cl;
      if (idx < end) {
        float v = stgw[u * 64 + lane];
        int dl = (int)(e[u] & NB_MASK);
        atomicAdd(&ssum[dl * 16 + k], v);
        if (k == 0) atomicAdd(&scnt[dl], 1);
      }
    }
  }
  __syncthreads();

  // epilogue: out = mean @ wl + bl + h @ wr for the 64 nodes of this bucket
  int j = t & 31;
  for (int nl = t >> 5; nl < NB; nl += 8) {
    int n = b * NB + nl;
    if (n >= n_nodes) break;
    float inv = 1.0f / fmaxf((float)scnt[nl], 1.0f);
    float acc = sbl[j];
    const float* hr = h + (size_t)n * 16;
#pragma unroll
    for (int kk = 0; kk < 16; ++kk) {
      float mv = ssum[nl * 16 + kk] * inv;
      acc += mv * swl[kk * 32 + j] + hr[kk] * swr[kk * 32 + j];
    }
    out[(size_t)n * 32 + j] = acc;
  }
}

// ---------------------------------------------------------------------------
// FALLBACK PATH (verified atomic kernels) — used only if ws too small or
// bucket table exceeds MAXBUCK.
// ---------------------------------------------------------------------------
__global__ __launch_bounds__(256) void scatter_kernel(
    const int* __restrict__ src, const int* __restrict__ dst,
    const float* __restrict__ h, float* __restrict__ summed,
    int* __restrict__ cnt, long long n_edges) {
  long long tid = (long long)blockIdx.x * blockDim.x + threadIdx.x;
  long long e = tid >> 4;
  int k = (int)(tid & 15);
  if (e >= n_edges) return;
  int s = src[e];
  int d = dst[e];
  float val = h[(size_t)s * 16 + k];
  atomicAdd(&summed[(size_t)d * 16 + k], val);
  if (k == 0) atomicAdd(&cnt[d], 1);
}

__global__ __launch_bounds__(256) void out_kernel(
    const float* __restrict__ h, const float* __restrict__ summed,
    const int* __restrict__ cnt,
    const float* __restrict__ wl, const float* __restrict__ bl,
    const float* __restrict__ wr, float* __restrict__ out, int n_nodes) {
  __shared__ float swl[512];
  __shared__ float swr[512];
  __shared__ float sbl[32];
  int t = threadIdx.x;
  for (int i = t; i < 512; i += 256) { swl[i] = wl[i]; swr[i] = wr[i]; }
  if (t < 32) sbl[t] = bl[t];
  __syncthreads();

  int gid = blockIdx.x * 256 + t;
  int n = gid >> 5;
  int j = gid & 31;
  if (n >= n_nodes) return;

  float inv = 1.0f / fmaxf((float)cnt[n], 1.0f);
  const float* hr = h + (size_t)n * 16;
  const float* sr = summed + (size_t)n * 16;
  float acc = sbl[j];
#pragma unroll
  for (int k = 0; k < 16; ++k) {
    acc += sr[k] * inv * swl[k * 32 + j] + hr[k] * swr[k * 32 + j];
  }
  out[(size_t)n * 32 + j] = acc;
}

// ---------------------------------------------------------------------------
extern "C" void kernel_launch(void* const* d_in, const int* in_sizes, int n_in,
                              void* d_out, int out_size, void* d_ws, size_t ws_size,
                              hipStream_t stream) {
  const float* x  = (const float*)d_in[0];
  const int* eidx = (const int*)d_in[1];
  const float* w1 = (const float*)d_in[2];
  const float* b1 = (const float*)d_in[3];
  const float* w2 = (const float*)d_in[4];
  const float* b2 = (const float*)d_in[5];
  const float* wl = (const float*)d_in[6];
  const float* bl = (const float*)d_in[7];
  const float* wr = (const float*)d_in[8];
  float* out = (float*)d_out;

  const int n_nodes = in_sizes[0] / D_IN_C;             // 100000
  const long long n_edges = (long long)in_sizes[1] / 2; // 3200000
  const int* src = eidx;
  const int* dst = eidx + n_edges;

  const int node_blocks = (n_nodes + 255) / 256;         // 391
  const int nbuck = (n_nodes + NB - 1) / NB;             // 1563
  const int epb_blocks = (int)((n_edges + EPB - 1) / EPB); // 250

  // New-path workspace layout.
  float*        h      = (float*)d_ws;                       // N*16 f32
  int*          gcount = (int*)(h + (size_t)n_nodes * 16);   // nbuck
  int*          cursor = gcount + nbuck;                     // nbuck
  int*          base   = cursor + nbuck;                     // nbuck+1
  unsigned int* ebuf   = (unsigned int*)(base + nbuck + 1);  // E u32

  size_t need = ((size_t)n_nodes * 16 + 3ull * nbuck + 1 + (size_t)n_edges) * 4;

  if (ws_size >= need && nbuck <= MAXBUCK) {
    // ---- coarse-bucket counting sort + DMA-gather aggregation ----
    mlp_kernel<<<node_blocks, 256, 0, stream>>>(
        x, w1, b1, w2, b2, h, nullptr, nullptr, gcount, nbuck, n_nodes);
    hist_kernel<<<epb_blocks, 1024, 0, stream>>>(dst, gcount, nbuck, (int)n_edges);
    scan_kernel<<<1, 256, 0, stream>>>(gcount, base, cursor, nbuck);
    bin_kernel<<<epb_blocks, 1024, 0, stream>>>(src, dst, cursor, ebuf,
                                                nbuck, (int)n_edges);
    agg_out_kernel<<<nbuck, 256, 0, stream>>>(h, ebuf, base, wl, bl, wr, out,
                                              n_nodes);
  } else {
    // ---- fallback: verified atomic path ----
    float* summed = h + (size_t)n_nodes * 16;
    int*   fcnt   = (int*)(summed + (size_t)n_nodes * 16);
    mlp_kernel<<<node_blocks, 256, 0, stream>>>(
        x, w1, b1, w2, b2, h, summed, fcnt, nullptr, 0, n_nodes);
    {
      long long total = n_edges * 16;
      int blocks = (int)((total + 255) / 256);
      scatter_kernel<<<blocks, 256, 0, stream>>>(src, dst, h, summed, fcnt, n_edges);
    }
    {
      long long total = (long long)n_nodes * 32;
      int blocks = (int)((total + 255) / 256);
      out_kernel<<<blocks, 256, 0, stream>>>(h, summed, fcnt, wl, bl, wr, out, n_nodes);
    }
  }
}